// Round 1
// baseline (595.550 us; speedup 1.0000x reference)
//
#include <hip/hip_runtime.h>
#include <hip/hip_fp16.h>

// Problem: B=8, C=64, T=128, N=207; KS=7, PAD=3; D_K=D_V=64.
// out[b,o,t,n] = sum_i softmax_i( Q[b,o,t,n] * Kpad[b,o,t+i-3,n] ) * Vpad[b,o,t+i-3,n]
// where Q/K/V are 64->64 channel projections (+bias), pads are exact zeros
// (applied AFTER bias), and the zero scores DO participate in the softmax.

#define C_DIM 64
#define T_DIM 128
#define N_DIM 207
#define O_DIM 64
#define TT 26          // output t rows per block
#define TS 32          // staged t rows (TT + 2*3 halo)
#define NN 8           // n columns per block
#define CSTRIDE (T_DIM * N_DIM)

__global__ __launch_bounds__(256, 2)
void attn_conv_fused(const float* __restrict__ q,
                     const float* __restrict__ k,
                     const float* __restrict__ v,
                     const float* __restrict__ Wq, const float* __restrict__ bq,
                     const float* __restrict__ Wk, const float* __restrict__ bk,
                     const float* __restrict__ Wv, const float* __restrict__ bv,
                     float* __restrict__ out)
{
    // 64 KB total: exactly fits 2 blocks/CU on 160 KB LDS.
    __shared__ __half Ks[O_DIM][TS][NN];   // 32 KB
    __shared__ __half Vs[O_DIM][TS][NN];   // 32 KB

    const int nb = blockIdx.x;     // 0..25
    const int tt = blockIdx.y;     // 0..4
    const int b  = blockIdx.z;     // 0..7

    const int tid  = threadIdx.x;
    const int trow = tid >> 3;     // 0..31 staged t row
    const int nloc = tid & 7;      // 0..7
    const int t0 = tt * TT;
    const int tg = t0 - 3 + trow;  // global t of this staged position
    const int n  = nb * NN + nloc;

    const bool valid_pos = (tg >= 0) && (tg < T_DIM) && (n < N_DIM);
    // clamped-safe base address; invalid lanes load a real address, result discarded
    const int tg_s = valid_pos ? tg : 0;
    const int n_s  = valid_pos ? n  : 0;
    const int base = (b * C_DIM * T_DIM + tg_s) * N_DIM + n_s;

    float x[C_DIM];

    // ---------------- Phase A1: K projection -> LDS (fp16) ----------------
    #pragma unroll
    for (int c = 0; c < C_DIM; ++c) {
        float t = k[base + c * CSTRIDE];
        x[c] = valid_pos ? t : 0.0f;
    }
    for (int o = 0; o < O_DIM; ++o) {
        const float* __restrict__ w = Wk + o * C_DIM;   // wave-uniform -> s_load
        float a0 = 0.f, a1 = 0.f, a2 = 0.f, a3 = 0.f;
        #pragma unroll
        for (int c = 0; c < C_DIM; c += 4) {
            a0 = fmaf(w[c + 0], x[c + 0], a0);
            a1 = fmaf(w[c + 1], x[c + 1], a1);
            a2 = fmaf(w[c + 2], x[c + 2], a2);
            a3 = fmaf(w[c + 3], x[c + 3], a3);
        }
        float r = (a0 + a1) + (a2 + a3) + bk[o];
        Ks[o][trow][nloc] = __float2half(valid_pos ? r : 0.0f);  // pad rows = exact 0
    }

    // ---------------- Phase A2: V projection -> LDS (fp16) ----------------
    #pragma unroll
    for (int c = 0; c < C_DIM; ++c) {
        float t = v[base + c * CSTRIDE];
        x[c] = valid_pos ? t : 0.0f;
    }
    for (int o = 0; o < O_DIM; ++o) {
        const float* __restrict__ w = Wv + o * C_DIM;
        float a0 = 0.f, a1 = 0.f, a2 = 0.f, a3 = 0.f;
        #pragma unroll
        for (int c = 0; c < C_DIM; c += 4) {
            a0 = fmaf(w[c + 0], x[c + 0], a0);
            a1 = fmaf(w[c + 1], x[c + 1], a1);
            a2 = fmaf(w[c + 2], x[c + 2], a2);
            a3 = fmaf(w[c + 3], x[c + 3], a3);
        }
        float r = (a0 + a1) + (a2 + a3) + bv[o];
        Vs[o][trow][nloc] = __float2half(valid_pos ? r : 0.0f);
    }

    // Output ownership: staged rows 3..28 are the TT=26 output rows.
    const bool is_out = (trow >= 3) && (trow < 3 + TT) && (tg < T_DIM) && (n < N_DIM);

    // Preload this thread's q column (fp32, kept exact in registers) before barrier
    #pragma unroll
    for (int c = 0; c < C_DIM; ++c) {
        float t = q[base + c * CSTRIDE];
        x[c] = is_out ? t : 0.0f;
    }

    __syncthreads();

    // ---------------- Phase B: per-o Q recompute + 7-tap softmax ----------------
    if (is_out) {
        const int obase = ((b * O_DIM) * T_DIM + tg) * N_DIM + n;
        for (int o = 0; o < O_DIM; ++o) {
            const float* __restrict__ w = Wq + o * C_DIM;
            float a0 = 0.f, a1 = 0.f, a2 = 0.f, a3 = 0.f;
            #pragma unroll
            for (int c = 0; c < C_DIM; c += 4) {
                a0 = fmaf(w[c + 0], x[c + 0], a0);
                a1 = fmaf(w[c + 1], x[c + 1], a1);
                a2 = fmaf(w[c + 2], x[c + 2], a2);
                a3 = fmaf(w[c + 3], x[c + 3], a3);
            }
            const float qv = (a0 + a1) + (a2 + a3) + bq[o];

            float s[7];
            #pragma unroll
            for (int i = 0; i < 7; ++i)
                s[i] = qv * __half2float(Ks[o][trow - 3 + i][nloc]);

            float m = s[0];
            #pragma unroll
            for (int i = 1; i < 7; ++i) m = fmaxf(m, s[i]);

            float den = 0.f, num = 0.f;
            #pragma unroll
            for (int i = 0; i < 7; ++i) {
                float e = __expf(s[i] - m);
                den += e;
                num = fmaf(e, __half2float(Vs[o][trow - 3 + i][nloc]), num);
            }
            out[obase + o * (T_DIM * N_DIM)] = num / den;
        }
    }
}

extern "C" void kernel_launch(void* const* d_in, const int* in_sizes, int n_in,
                              void* d_out, int out_size, void* d_ws, size_t ws_size,
                              hipStream_t stream)
{
    const float* q  = (const float*)d_in[0];
    const float* k  = (const float*)d_in[1];
    const float* v  = (const float*)d_in[2];
    const float* Wq = (const float*)d_in[3];
    const float* bq = (const float*)d_in[4];
    const float* Wk = (const float*)d_in[5];
    const float* bk = (const float*)d_in[6];
    const float* Wv = (const float*)d_in[7];
    const float* bv = (const float*)d_in[8];
    float* o = (float*)d_out;

    const int B = 8;
    const int n_tiles = (N_DIM + NN - 1) / NN;   // 26
    const int t_tiles = (T_DIM + TT - 1) / TT;   // 5

    dim3 grid(n_tiles, t_tiles, B);
    dim3 block(256);
    hipLaunchKernelGGL(attn_conv_fused, grid, block, 0, stream,
                       q, k, v, Wq, bq, Wk, bk, Wv, bv, o);
}

// Round 3
// 370.653 us; speedup vs baseline: 1.6068x; 1.6068x over previous
//
#include <hip/hip_runtime.h>

typedef _Float16 h2 __attribute__((ext_vector_type(2)));

#define B_DIM 8
#define C_DIM 64
#define T_DIM 128
#define N_DIM 207
#define O_DIM 64
#define CSTR  (T_DIM * N_DIM)

// ---------------------------------------------------------------------------
// Kernel 0: pack Wq|Wk|Wv (fp32, [64 o][64 c]) into fp16 halves in d_ws.
// Layout: ws_h[arr][o][c], arr: 0=q, 1=k, 2=v.  24 KB total.
// ---------------------------------------------------------------------------
__global__ void pack_w(const float* __restrict__ Wq,
                       const float* __restrict__ Wk,
                       const float* __restrict__ Wv,
                       _Float16* __restrict__ ws)
{
    int i = threadIdx.x + blockIdx.x * blockDim.x;
    const int per = O_DIM * C_DIM;          // 4096
    for (int m = i; m < 3 * per; m += blockDim.x * gridDim.x) {
        int arr = m / per, rem = m % per;
        const float* W = (arr == 0) ? Wq : (arr == 1) ? Wk : Wv;
        ws[m] = (_Float16)W[rem];
    }
}

// ---------------------------------------------------------------------------
// Main kernel: t-marching fused QKV projection + 7-tap conv softmax.
// Block: 256 thr = 64 n-lanes x 4 waves; wave w owns o = osl*16 + w*4 + j.
// Per step r: stage x-row (t0-3+r) to LDS (fp16), project Q/K/V for 4 o's via
// v_dot2 (W rows via s_load from ws), slide 7-tap K/V + 4-deep Q reg windows,
// emit output row to = t0 + r - 6.
// ---------------------------------------------------------------------------
__global__ __launch_bounds__(256, 2)
void attn_march(const float* __restrict__ q,
                const float* __restrict__ k,
                const float* __restrict__ v,
                const float* __restrict__ bq,
                const float* __restrict__ bk,
                const float* __restrict__ bv,
                const unsigned int* __restrict__ wpk,   // packed fp16 W pairs
                float* __restrict__ out)
{
    // x staging: [arr][n(64)][34 dwords = 68 halves (64 + 4 pad)]  = 26112 B
    __shared__ unsigned int xsd[3][64][34];

    const int tid  = threadIdx.x;
    const int lane = tid & 63;          // n offset within tile
    const int wv   = tid >> 6;          // wave id 0..3 (== staging c-group)

    const int nb  = blockIdx.x >> 2;    // n tile 0..3
    const int tc  = blockIdx.x & 3;     // t chunk 0..3
    const int b   = blockIdx.y;         // batch
    const int osl = blockIdx.z;         // o slice 0..3

    const int n    = nb * 64 + lane;
    const int n_s  = (n < N_DIM) ? n : (N_DIM - 1);
    const int t0   = tc * 32;
    const int obase = osl * 16 + wv * 4;

    const float* srcs[3] = { q, k, v };

    // register prefetch buffer: this thread stages c = wv*16 .. wv*16+15
    float pf[3][16];
    {
        const int tg = t0 - 3;
        const int tgc = (tg < 0) ? 0 : tg;
        #pragma unroll
        for (int arr = 0; arr < 3; ++arr) {
            const float* s = srcs[arr] + ((size_t)b * C_DIM + wv * 16) * CSTR
                             + (size_t)tgc * N_DIM + n_s;
            #pragma unroll
            for (int i = 0; i < 16; ++i) pf[arr][i] = s[i * CSTR];
        }
    }

    // sliding windows (registers, shift-by-one each step)
    float Kw[4][7], Vw[4][7], Qw[4][4];
    #pragma unroll
    for (int j = 0; j < 4; ++j) {
        #pragma unroll
        for (int i = 0; i < 7; ++i) { Kw[j][i] = 0.f; Vw[j][i] = 0.f; }
        #pragma unroll
        for (int i = 0; i < 4; ++i) Qw[j][i] = 0.f;
    }

    for (int r = 0; r < 38; ++r) {
        __syncthreads();                 // readers of previous row done

        // ---- write staged row r (from pf) into LDS as packed fp16 ----
        #pragma unroll
        for (int arr = 0; arr < 3; ++arr) {
            #pragma unroll
            for (int m = 0; m < 8; ++m) {
                auto ph = __builtin_amdgcn_cvt_pkrtz(pf[arr][2 * m], pf[arr][2 * m + 1]);
                xsd[arr][lane][wv * 8 + m] = __builtin_bit_cast(unsigned int, ph);
            }
        }
        __syncthreads();                 // row r visible

        // ---- prefetch row r+1 (in flight during compute) ----
        if (r < 37) {
            const int tg1 = t0 - 3 + r + 1;
            const int tgc = (tg1 < 0) ? 0 : (tg1 > T_DIM - 1 ? T_DIM - 1 : tg1);
            #pragma unroll
            for (int arr = 0; arr < 3; ++arr) {
                const float* s = srcs[arr] + ((size_t)b * C_DIM + wv * 16) * CSTR
                                 + (size_t)tgc * N_DIM + n_s;
                #pragma unroll
                for (int i = 0; i < 16; ++i) pf[arr][i] = s[i * CSTR];
            }
        }

        const int tg = t0 - 3 + r;
        const bool rowv = (tg >= 0) && (tg < T_DIM);

        // ---- shift windows ----
        #pragma unroll
        for (int j = 0; j < 4; ++j) {
            #pragma unroll
            for (int i = 0; i < 6; ++i) { Kw[j][i] = Kw[j][i + 1]; Vw[j][i] = Vw[j][i + 1]; }
            #pragma unroll
            for (int i = 0; i < 3; ++i) Qw[j][i] = Qw[j][i + 1];
        }

        // ---- projections: per array, cache x column, 4 wave-uniform o's ----
        float pr[3][4];
        #pragma unroll
        for (int arr = 0; arr < 3; ++arr) {
            unsigned int xr[32];
            #pragma unroll
            for (int qq = 0; qq < 16; ++qq) {
                uint2 rd = *(const uint2*)&xsd[arr][lane][2 * qq];
                xr[2 * qq] = rd.x; xr[2 * qq + 1] = rd.y;
            }
            const float* bias_p = (arr == 0) ? bq : (arr == 1) ? bk : bv;
            #pragma unroll
            for (int j = 0; j < 4; ++j) {
                const int o_u = __builtin_amdgcn_readfirstlane(obase + j);
                const unsigned int* wr = wpk + ((size_t)arr * 64 + o_u) * 32;
                float a0 = 0.f, a1 = 0.f;
                #pragma unroll
                for (int m = 0; m < 32; m += 2) {
                    a0 = __builtin_amdgcn_fdot2(__builtin_bit_cast(h2, wr[m]),
                                                __builtin_bit_cast(h2, xr[m]), a0, false);
                    a1 = __builtin_amdgcn_fdot2(__builtin_bit_cast(h2, wr[m + 1]),
                                                __builtin_bit_cast(h2, xr[m + 1]), a1, false);
                }
                pr[arr][j] = a0 + a1 + bias_p[o_u];
            }
        }

        #pragma unroll
        for (int j = 0; j < 4; ++j) {
            Qw[j][3] = pr[0][j];
            Kw[j][6] = rowv ? pr[1][j] : 0.f;   // pads are exact zeros (post-bias)
            Vw[j][6] = rowv ? pr[2][j] : 0.f;
        }

        // ---- output row to = tg - 3 ----
        const int to = t0 + r - 6;
        if (r >= 6 && to < T_DIM && n < N_DIM) {
            #pragma unroll
            for (int j = 0; j < 4; ++j) {
                const float qv = Qw[j][0];
                float s[7];
                #pragma unroll
                for (int i = 0; i < 7; ++i) s[i] = qv * Kw[j][i];
                float mx = s[0];
                #pragma unroll
                for (int i = 1; i < 7; ++i) mx = fmaxf(mx, s[i]);
                float den = 0.f, num = 0.f;
                #pragma unroll
                for (int i = 0; i < 7; ++i) {
                    float e = __expf(s[i] - mx);
                    den += e;
                    num = fmaf(e, Vw[j][i], num);
                }
                out[(((size_t)b * O_DIM + (obase + j)) * T_DIM + to) * N_DIM + n]
                    = num * __builtin_amdgcn_rcpf(den);
            }
        }
    }
}

extern "C" void kernel_launch(void* const* d_in, const int* in_sizes, int n_in,
                              void* d_out, int out_size, void* d_ws, size_t ws_size,
                              hipStream_t stream)
{
    const float* q  = (const float*)d_in[0];
    const float* k  = (const float*)d_in[1];
    const float* v  = (const float*)d_in[2];
    const float* Wq = (const float*)d_in[3];
    const float* bq = (const float*)d_in[4];
    const float* Wk = (const float*)d_in[5];
    const float* bk = (const float*)d_in[6];
    const float* Wv = (const float*)d_in[7];
    const float* bv = (const float*)d_in[8];
    float* o = (float*)d_out;

    _Float16* ws_h = (_Float16*)d_ws;   // 24 KB used

    hipLaunchKernelGGL(pack_w, dim3(3), dim3(256), 0, stream, Wq, Wk, Wv, ws_h);

    dim3 grid(16, B_DIM, 4);            // (nb*4 + tc, b, osl)
    dim3 block(256);
    hipLaunchKernelGGL(attn_march, grid, block, 0, stream,
                       q, k, v, bq, bk, bv, (const unsigned int*)ws_h, o);
}

// Round 4
// 267.086 us; speedup vs baseline: 2.2298x; 1.3878x over previous
//
#include <hip/hip_runtime.h>

typedef _Float16 half8 __attribute__((ext_vector_type(8)));
typedef float floatx4 __attribute__((ext_vector_type(4)));

#define B_DIM 8
#define C_DIM 64
#define T_DIM 128
#define N_DIM 207
#define O_DIM 64
#define CSTR  (T_DIM * N_DIM)

// ---------------------------------------------------------------------------
// Kernel 0: pack Wq|Wk|Wv (fp32 [64 o][64 c]) -> fp16 in d_ws. [arr][o][c].
// ---------------------------------------------------------------------------
__global__ void pack_w(const float* __restrict__ Wq,
                       const float* __restrict__ Wk,
                       const float* __restrict__ Wv,
                       _Float16* __restrict__ ws)
{
    int i = threadIdx.x + blockIdx.x * blockDim.x;
    const int per = O_DIM * C_DIM;          // 4096
    for (int m = i; m < 3 * per; m += blockDim.x * gridDim.x) {
        int arr = m / per, rem = m % per;
        const float* W = (arr == 0) ? Wq : (arr == 1) ? Wk : Wv;
        ws[m] = (_Float16)W[rem];
    }
}

// ---------------------------------------------------------------------------
// Main: t-marching MFMA kernel.
// Block 256 thr = 4 waves. Tile per t-step: [64 o][16 n].
// Wave w: o-slice w*16, A = W-frags (registers), B = X-frags from LDS
// (fragment-ordered: lane-indexed 16B chunks). C-layout gives each lane 4
// (o,n) positions -> rolling K/V 7-windows + Q 4-delay in registers.
// ---------------------------------------------------------------------------
__global__ __launch_bounds__(256, 3)
void attn_mfma(const float* __restrict__ q,
               const float* __restrict__ k,
               const float* __restrict__ v,
               const float* __restrict__ bq,
               const float* __restrict__ bk,
               const float* __restrict__ bv,
               const _Float16* __restrict__ wpk,
               float* __restrict__ out)
{
    // [buf][arr*2+kk][lane] fragment-ordered X staging: 2*6*64*16B = 12288 B
    __shared__ half8 xsf[2][6][64];

    const int tid  = threadIdx.x;
    const int lane = tid & 63;
    const int wv   = tid >> 6;        // wave = o-slice
    const int nq   = lane & 15;       // D col (n), A row (m)
    const int qd   = lane >> 4;       // quad

    const int nb = blockIdx.x;        // 0..12 (16 n each)
    const int tc = blockIdx.y;        // 0..7  (16 t each)
    const int b  = blockIdx.z;        // 0..7

    const int t0 = tc * 16;
    const int o0 = wv * 16;
    const int n0 = nb * 16;

    // ---- staging mapping: thread -> (n=sn, c-pairs cp2 & cp2+16) ----
    const int sn  = tid & 15;
    const int cp2 = tid >> 4;         // 0..15
    const int wq  = cp2 >> 2;         // frag quad of staged elements
    const int jp  = cp2 & 3;          // dword-pair index within frag

    const int n_sc = min(n0 + sn, N_DIM - 1);
    const float* qb = q + (size_t)b * C_DIM * CSTR + n_sc;
    const float* kb = k + (size_t)b * C_DIM * CSTR + n_sc;
    const float* vb = v + (size_t)b * C_DIM * CSTR + n_sc;

    // ---- loop-invariant A-fragments: W[o0+m][k], m=nq, k=qd*8+j+kk*32 ----
    half8 af[3][2];
    #pragma unroll
    for (int arr = 0; arr < 3; ++arr)
        #pragma unroll
        for (int kk = 0; kk < 2; ++kk)
            af[arr][kk] = *(const half8*)(wpk + ((size_t)(arr * 64 + o0 + nq) * 64
                                                 + qd * 8 + kk * 32));

    // ---- bias per lane-reg: D row o_l = qd*4+reg ----
    float bq_r[4], bk_r[4], bv_r[4];
    #pragma unroll
    for (int j = 0; j < 4; ++j) {
        const int og = o0 + qd * 4 + j;
        bq_r[j] = bq[og]; bk_r[j] = bk[og]; bv_r[j] = bv[og];
    }

    // ---- rolling windows ----
    float Kw[4][7], Vw[4][7], Qd4[4][4];
    #pragma unroll
    for (int j = 0; j < 4; ++j) {
        #pragma unroll
        for (int i = 0; i < 7; ++i) { Kw[j][i] = 0.f; Vw[j][i] = 0.f; }
        #pragma unroll
        for (int i = 0; i < 4; ++i) Qd4[j][i] = 0.f;
    }

    unsigned int* xw = (unsigned int*)&xsf[0][0][0];

    // ---- initial prefetch (row t0-3) ----
    float pf[3][4];
    {
        const int tcl = max(t0 - 3, 0);
        const float* bases[3] = { qb, kb, vb };
        #pragma unroll
        for (int arr = 0; arr < 3; ++arr) {
            const float* p = bases[arr] + (size_t)tcl * N_DIM;
            pf[arr][0] = p[(2 * cp2    ) * CSTR];
            pf[arr][1] = p[(2 * cp2 + 1) * CSTR];
            pf[arr][2] = p[(2 * cp2 + 32) * CSTR];
            pf[arr][3] = p[(2 * cp2 + 33) * CSTR];
        }
    }

    for (int r = 0; r < 22; ++r) {
        const int buf = r & 1;

        // ---- scatter staged row into fragment-ordered LDS ----
        #pragma unroll
        for (int arr = 0; arr < 3; ++arr) {
            auto p0 = __builtin_amdgcn_cvt_pkrtz(pf[arr][0], pf[arr][1]);  // kk=0
            auto p1 = __builtin_amdgcn_cvt_pkrtz(pf[arr][2], pf[arr][3]);  // kk=1
            xw[buf * 1536 + ((arr * 2 + 0) * 64 + wq * 16 + sn) * 4 + jp]
                = __builtin_bit_cast(unsigned int, p0);
            xw[buf * 1536 + ((arr * 2 + 1) * 64 + wq * 16 + sn) * 4 + jp]
                = __builtin_bit_cast(unsigned int, p1);
        }

        // ---- prefetch row r+1 ----
        if (r < 21) {
            const int tg1 = t0 - 2 + r;
            const int tcl = min(max(tg1, 0), T_DIM - 1);
            const float* bases[3] = { qb, kb, vb };
            #pragma unroll
            for (int arr = 0; arr < 3; ++arr) {
                const float* p = bases[arr] + (size_t)tcl * N_DIM;
                pf[arr][0] = p[(2 * cp2    ) * CSTR];
                pf[arr][1] = p[(2 * cp2 + 1) * CSTR];
                pf[arr][2] = p[(2 * cp2 + 32) * CSTR];
                pf[arr][3] = p[(2 * cp2 + 33) * CSTR];
            }
        }

        __syncthreads();   // staged row visible (double-buffer: 1 barrier/step)

        // ---- projections via MFMA ----
        floatx4 aq = {0.f, 0.f, 0.f, 0.f};
        floatx4 ak = {0.f, 0.f, 0.f, 0.f};
        floatx4 av = {0.f, 0.f, 0.f, 0.f};
        aq = __builtin_amdgcn_mfma_f32_16x16x32_f16(af[0][0], xsf[buf][0][lane], aq, 0, 0, 0);
        aq = __builtin_amdgcn_mfma_f32_16x16x32_f16(af[0][1], xsf[buf][1][lane], aq, 0, 0, 0);
        ak = __builtin_amdgcn_mfma_f32_16x16x32_f16(af[1][0], xsf[buf][2][lane], ak, 0, 0, 0);
        ak = __builtin_amdgcn_mfma_f32_16x16x32_f16(af[1][1], xsf[buf][3][lane], ak, 0, 0, 0);
        av = __builtin_amdgcn_mfma_f32_16x16x32_f16(af[2][0], xsf[buf][4][lane], av, 0, 0, 0);
        av = __builtin_amdgcn_mfma_f32_16x16x32_f16(af[2][1], xsf[buf][5][lane], av, 0, 0, 0);

        const int tg = t0 - 3 + r;
        const bool rowv = (tg >= 0) && (tg < T_DIM);

        // ---- shift + insert windows ----
        #pragma unroll
        for (int j = 0; j < 4; ++j) {
            #pragma unroll
            for (int i = 0; i < 6; ++i) { Kw[j][i] = Kw[j][i + 1]; Vw[j][i] = Vw[j][i + 1]; }
            #pragma unroll
            for (int i = 0; i < 3; ++i) Qd4[j][i] = Qd4[j][i + 1];
            Kw[j][6]  = rowv ? (ak[j] + bk_r[j]) : 0.f;  // pad rows exact 0 (post-bias)
            Vw[j][6]  = rowv ? (av[j] + bv_r[j]) : 0.f;
            Qd4[j][3] = aq[j] + bq_r[j];
        }

        // ---- emit output row to = t0 + r - 6 ----
        if (r >= 6) {
            const int to  = t0 + r - 6;
            const int n_g = n0 + nq;
            if (n_g < N_DIM) {
                #pragma unroll
                for (int j = 0; j < 4; ++j) {
                    const float qv = Qd4[j][0] * 1.44269504f;  // log2(e): exp2 domain
                    float s[7];
                    #pragma unroll
                    for (int i = 0; i < 7; ++i) s[i] = qv * Kw[j][i];
                    float mx = s[0];
                    #pragma unroll
                    for (int i = 1; i < 7; ++i) mx = fmaxf(mx, s[i]);
                    float den = 0.f, num = 0.f;
                    #pragma unroll
                    for (int i = 0; i < 7; ++i) {
                        float e = exp2f(s[i] - mx);
                        den += e;
                        num = fmaf(e, Vw[j][i], num);
                    }
                    out[((size_t)(b * O_DIM + o0 + qd * 4 + j) * T_DIM + to) * N_DIM + n_g]
                        = num * __builtin_amdgcn_rcpf(den);
                }
            }
        }
    }
}

extern "C" void kernel_launch(void* const* d_in, const int* in_sizes, int n_in,
                              void* d_out, int out_size, void* d_ws, size_t ws_size,
                              hipStream_t stream)
{
    const float* q  = (const float*)d_in[0];
    const float* k  = (const float*)d_in[1];
    const float* v  = (const float*)d_in[2];
    const float* Wq = (const float*)d_in[3];
    const float* bq = (const float*)d_in[4];
    const float* Wk = (const float*)d_in[5];
    const float* bk = (const float*)d_in[6];
    const float* Wv = (const float*)d_in[7];
    const float* bv = (const float*)d_in[8];
    float* o = (float*)d_out;

    _Float16* ws_h = (_Float16*)d_ws;   // 24 KB used

    hipLaunchKernelGGL(pack_w, dim3(3), dim3(256), 0, stream, Wq, Wk, Wv, ws_h);

    dim3 grid(13, 8, B_DIM);            // (n-tile, t-chunk, b) = 832 blocks
    dim3 block(256);
    hipLaunchKernelGGL(attn_mfma, grid, block, 0, stream,
                       q, k, v, bq, bk, bv, (const _Float16*)ws_h, o);
}